// Round 12
// baseline (605.185 us; speedup 1.0000x reference)
//
#include <hip/hip_runtime.h>
#include <hip/hip_bf16.h>

// Problem constants (match reference setup_inputs)
#define N_NODES 50000
#define E_EDGES 600000
#define C_CH    130
#define CP      160      // padded channel width for weights/frags
#define L_LAYERS 4
#define BN_EPS  1e-5f
#define TS      168      // LDS t-tile stride (ushorts)
#define PLANE   ((size_t)N_NODES * 8)   // dwords per channel-plane (1.6 MB)

#define TAIL_BLKS 196                // tail-plane blocks (run FIRST)
#define L0_MAIN_BLKS 12500           // (N+3)/4 wave-per-node (L0 index gather)
#define DENSE_MAIN_BLKS 100000       // 8 planes x 12500 node-waves / 4 per block

// prep block ranges: packB(45, LDS-staged) | padWh2(1) | ss(9) | feat(196) | zero(49)
#define PACKB_BLKS 45
#define PREP_BLKS  (PACKB_BLKS + 1 + 9)   // 55
#define FEAT_BLKS  196
#define ZERO_BLKS  49

typedef __bf16 bf16x8 __attribute__((ext_vector_type(8)));
typedef float  f32x4  __attribute__((ext_vector_type(4)));
typedef unsigned u32x4 __attribute__((ext_vector_type(4)));

// fp32 -> bf16 RNE
__device__ __forceinline__ unsigned short f2bf(float f) {
    unsigned u = __float_as_uint(f);
    unsigned r = (u + 0x7FFFu + ((u >> 16) & 1u)) >> 16;
    return (unsigned short)r;
}
__device__ __forceinline__ unsigned packbf(float lo, float hi) {
    return (unsigned)f2bf(lo) | ((unsigned)f2bf(hi) << 16);
}
__device__ __forceinline__ float bflo(unsigned d) { return __uint_as_float(d << 16); }
__device__ __forceinline__ float bfhi(unsigned d) { return __uint_as_float(d & 0xFFFF0000u); }

// ---------------------------------------------------------------------------
// Mega prep: [0,45) packB LDS-staged | 45 padWh2 | [46,55) ss |
//            [55,251) tail feats + xtk | [251,300) zero indeg
// ---------------------------------------------------------------------------
__global__ __launch_bounds__(256) void k_prep(
        const float* __restrict__ W1, const float* __restrict__ W2,
        const float* __restrict__ Wh1, const float* __restrict__ Wh2,
        const float* __restrict__ b1, const float* __restrict__ b2,
        const float* __restrict__ gamma, const float* __restrict__ beta,
        const float* __restrict__ rmean, const float* __restrict__ rvar,
        const float* __restrict__ bh1,
        const int* __restrict__ xt, const int* __restrict__ xk,
        const float* __restrict__ xs,
        unsigned short* __restrict__ Bp, float* __restrict__ Wh2p,
        float* __restrict__ ss, unsigned short* __restrict__ xtk,
        unsigned* __restrict__ ht, unsigned* __restrict__ htm,
        int* __restrict__ indeg) {
    int blk = blockIdx.x;
    int tid = threadIdx.x;
    if (blk < PACKB_BLKS) {
        __shared__ float wlds[32][132];          // +2 pad
        int g = blk / 5, ks = blk - g * 5;
        const float* W;
        if (g < 8) W = (g & 1) ? (W2 + (size_t)(g >> 1) * C_CH * C_CH)
                               : (W1 + (size_t)(g >> 1) * C_CH * C_CH);
        else       W = Wh1;
        for (int i = tid; i < 32 * C_CH; i += 256) {
            int kk = i / C_CH, c = i - kk * C_CH;
            int k = ks * 32 + kk;
            wlds[kk][c] = (k < C_CH) ? W[(size_t)k * C_CH + c] : 0.f;
        }
        __syncthreads();
        for (int q = tid; q < 640; q += 256) {   // 10 frags x 64 lanes
            int f = q >> 6, l = q & 63;
            int kg = l >> 4, c = f * 16 + (l & 15);
            union { unsigned short s[8]; uint4 u; } out;
#pragma unroll
            for (int j = 0; j < 8; j++) {
                float v = (c < C_CH) ? wlds[kg * 8 + j][c] : 0.f;
                out.s[j] = f2bf(v);
            }
            *(uint4*)(Bp + ((size_t)((g * 50 + ks * 10 + f) * 64 + l) * 8)) = out.u;
        }
        return;
    }
    if (blk == PACKB_BLKS) {
        for (int i = tid; i < CP * 2; i += 256) {
            int r = i >> 1, c = i & 1;
            Wh2p[i] = (r < C_CH) ? Wh2[r * 2 + c] : 0.f;
        }
        return;
    }
    if (blk < PREP_BLKS) {
        int g = blk - (PACKB_BLKS + 1);      // 0..8
        int c = tid;
        if (c >= CP) return;
        float scale = 1.f, shift = 0.f;
        if (g < 2 * L_LAYERS) {
            int l = g >> 1;
            if ((g & 1) == 0) {
                if (c < C_CH) shift = b1[l * C_CH + c];
            } else if (c < C_CH) {
                float s = gamma[l * C_CH + c] * rsqrtf(rvar[l * C_CH + c] + BN_EPS);
                scale = s;
                shift = (b2[l * C_CH + c] - rmean[l * C_CH + c]) * s + beta[l * C_CH + c];
            }
        } else {
            if (c < C_CH) shift = bh1[c];
        }
        ss[(g * 2 + 0) * CP + c] = scale;
        ss[(g * 2 + 1) * CP + c] = shift;
        return;
    }
    if (blk < PREP_BLKS + FEAT_BLKS) {
        int n = (blk - PREP_BLKS) * 256 + tid;
        if (n < N_NODES) {
            int t = xt[n];                       // 0..31
            int k = xk[n]; k = k < 0 ? 0 : (k > 95 ? 95 : k);
            xtk[n] = (unsigned short)(t | (k << 5));
            float a = xs[2 * n], b = xs[2 * n + 1];
            ht[n]  = packbf(a, b);
            htm[n] = packbf(fmaxf(a, 0.f), fmaxf(b, 0.f));
        }
        return;
    }
    {
        int slot = (blk - PREP_BLKS - FEAT_BLKS) * 256 + tid;
        if (slot < N_NODES / 4)
            ((int4*)indeg)[slot] = make_int4(0, 0, 0, 0);
    }
}

// ---------------------------------------------------------------------------
// CSR-by-dst build: rank from atomic return; fill without atomics
// ---------------------------------------------------------------------------
__global__ void k_indeg(const int* __restrict__ dst, int* __restrict__ indeg,
                        unsigned short* __restrict__ rank16) {
    int e = blockIdx.x * blockDim.x + threadIdx.x;
    if (e >= E_EDGES) return;
    int r = atomicAdd(&indeg[dst[e]], 1);
    __builtin_nontemporal_store((unsigned short)r, &rank16[e]);
}

__global__ void k_scan1(const int* __restrict__ indeg, int* __restrict__ localscan,
                        int* __restrict__ bsum) {
    __shared__ int lds[256];
    int tid = threadIdx.x;
    int base = blockIdx.x * 1024 + tid * 4;
    int v[4]; int s = 0;
#pragma unroll
    for (int r = 0; r < 4; r++) {
        int i = base + r;
        v[r] = (i < N_NODES) ? indeg[i] : 0;
        s += v[r];
    }
    lds[tid] = s;
    __syncthreads();
    for (int off = 1; off < 256; off <<= 1) {
        int x = (tid >= off) ? lds[tid - off] : 0;
        __syncthreads();
        lds[tid] += x;
        __syncthreads();
    }
    int excl = lds[tid] - s;
    int w = excl;
#pragma unroll
    for (int r = 0; r < 4; r++) {
        int i = base + r;
        if (i < N_NODES) localscan[i] = w;
        w += v[r];
    }
    if (tid == 255) bsum[blockIdx.x] = lds[255];
}

// merged scan2+scan3: each block wave-reduces its exclusive block offset
__global__ void k_scan23(int* __restrict__ rowstart, const int* __restrict__ bsum) {
    __shared__ int offs;
    int tid = threadIdx.x;
    int b = blockIdx.x;
    if (tid < 64) {
        int v = (tid < b) ? bsum[tid] : 0;
#pragma unroll
        for (int m = 1; m < 64; m <<= 1) v += __shfl_xor(v, m, 64);
        if (tid == 0) offs = v;
    }
    __syncthreads();
    int add = offs;
    int base = b * 1024 + tid * 4;
#pragma unroll
    for (int r = 0; r < 4; r++) {
        int i = base + r;
        if (i < N_NODES) rowstart[i] += add;
    }
    if (b == 0 && tid == 0) rowstart[N_NODES] = E_EDGES;
}

// csr[slot] = src | et<<16, slot = rowstart[d] + rank (no atomics)
__global__ void k_fill(const int* __restrict__ src, const int* __restrict__ dst,
                       const int* __restrict__ et,
                       const unsigned short* __restrict__ rank16,
                       const int* __restrict__ rowstart, int* __restrict__ csr) {
    int e = blockIdx.x * blockDim.x + threadIdx.x;
    if (e >= E_EDGES) return;
    int d = dst[e];
    __builtin_nontemporal_store(src[e] | (et[e] << 16), &csr[rowstart[d] + (int)rank16[e]]);
}

// ---------------------------------------------------------------------------
// Aggregation. blocks [0,TAIL_BLKS): tail plane (node/thread).
// L0 (template): wave-per-node index-histogram gather; persists cntf; writes
//                zm in PLANE layout.
// Dense: 8 channel-planes x wave-per-node; plane = blockIdx&7 pins each
//        1.6MB plane to one XCD's L2. 8 slots x 8 lanes x 4B; nt csr loads.
// ---------------------------------------------------------------------------
template<bool L0>
__global__ __launch_bounds__(256) void k_spmm(const unsigned* __restrict__ hm,
                                              const unsigned short* __restrict__ xtk,
                                              const unsigned* __restrict__ tmsg,
                                              const unsigned* __restrict__ ht,
                                              const int* __restrict__ rowstart,
                                              const int* __restrict__ csr,
                                              float4* __restrict__ cntf,
                                              unsigned* __restrict__ zm,
                                              unsigned* __restrict__ zt) {
    int b = blockIdx.x;
    if (b < TAIL_BLKS) {
        int n = b * 256 + threadIdx.x;
        if (n >= N_NODES) return;
        unsigned hn = ht[n];
        float a0 = bflo(hn), a1 = bfhi(hn);
        int rs = rowstart[n], re = rowstart[n + 1];
        for (int e = rs; e < re; ++e) {
            unsigned q = tmsg[(unsigned)csr[e] & 0xFFFFu];
            a0 += bflo(q); a1 += bfhi(q);
        }
        __builtin_nontemporal_store(packbf(a0, a1), &zt[n]);
        return;
    }
    int wave = threadIdx.x >> 6;
    int lane = threadIdx.x & 63;

    if (L0) {
        int n = (b - TAIL_BLKS) * 4 + wave;
        if (n >= N_NODES) return;
        int rs = rowstart[n], re = rowstart[n + 1];
        int c0 = 2 * lane, c1 = c0 + 1;
        int ce0 = 0, ce1 = 0, ce2 = 0;
        int xv_s = xtk[n];
        int ts = xv_s & 31, ks = 32 + (xv_s >> 5);
        int ia0 = (ts == c0) + (ks == c0);
        int ia1 = (ts == c1) + (ks == c1);
        for (int e = rs; e < re; e += 16) {
            unsigned p[16]; int xv[16];
#pragma unroll
            for (int r = 0; r < 16; r++) {
                int ee = e + r; ee = (ee < re) ? ee : (re - 1);
                p[r] = (unsigned)csr[ee];
            }
#pragma unroll
            for (int r = 0; r < 16; r++)
                xv[r] = xtk[p[r] & 0xFFFFu];
#pragma unroll
            for (int r = 0; r < 16; r++) {
                if (e + r < re) {
                    int t = xv[r] & 31, k = 32 + (xv[r] >> 5);
                    ia0 += (t == c0) + (k == c0);
                    ia1 += (t == c1) + (k == c1);
                    unsigned et = p[r] >> 16;
                    ce0 += (et == 0); ce1 += (et == 1); ce2 += (et == 2);
                }
            }
        }
        float a0 = (float)ia0, a1 = (float)ia1;
        if (lane == 0) {
            cntf[n] = make_float4((float)ce0, (float)ce1, (float)ce2, 0.f);
            a0 += (float)ce0; a1 += (float)ce1;
        } else if (lane == 1) {
            a0 += (float)ce2;
        }
        // PLANE-layout store: dword `lane` -> plane lane>>3, off lane&7
        __builtin_nontemporal_store(packbf(a0, a1),
            &zm[(size_t)(lane >> 3) * PLANE + (size_t)n * 8 + (lane & 7)]);
    } else {
        int bb = b - TAIL_BLKS;
        int plane = b & 7;                 // ties plane to XCD (blockIdx%8)
        int n = (bb >> 3) * 4 + wave;      // 0..49999
        if (n >= N_NODES) return;
        int rs = rowstart[n], re = rowstart[n + 1];
        int slot = lane >> 3;              // 8 edge slots
        int dw   = lane & 7;               // dword within 32B plane slice
        const unsigned* hp = hm + (size_t)plane * PLANE;
        float a0 = 0.f, a1 = 0.f;
        for (int e = rs; e < re; e += 32) {
            int idx[4]; unsigned s[4];
#pragma unroll
            for (int r = 0; r < 4; r++) {
                idx[r] = e + 8 * r + slot;
                int ee = (idx[r] < re) ? idx[r] : (re - 1);
                s[r] = (unsigned)__builtin_nontemporal_load(&csr[ee]) & 0xFFFFu;
            }
            unsigned d[4];
#pragma unroll
            for (int r = 0; r < 4; r++)
                d[r] = hp[(size_t)s[r] * 8 + dw];
#pragma unroll
            for (int r = 0; r < 4; r++) {
                if (idx[r] < re) { a0 += bflo(d[r]); a1 += bfhi(d[r]); }
            }
        }
#pragma unroll
        for (int m = 8; m <= 32; m <<= 1) {
            a0 += __shfl_xor(a0, m, 64);
            a1 += __shfl_xor(a1, m, 64);
        }
        if (slot == 0) {
            unsigned hn = hp[(size_t)n * 8 + dw];
            a0 += bflo(hn); a1 += bfhi(hn);
            if (plane == 0) {
                if (dw == 0)      { float4 c = cntf[n]; a0 += c.x; a1 += c.y; }
                else if (dw == 1) { a0 += cntf[n].z; }
            }
            __builtin_nontemporal_store(packbf(a0, a1),
                &zm[(size_t)plane * PLANE + (size_t)n * 8 + dw]);
        }
    }
}

// ---------------------------------------------------------------------------
// Fused MLP layer, 128-row blocks: h_out = relu(BN(relu(z@W1+b1)@W2+b2))
// A-operand and output in PLANE layout; output via t_lds -> per-plane
// coalesced nt stores.
// ---------------------------------------------------------------------------
__global__ __launch_bounds__(256) void k_mlp(const unsigned* __restrict__ zm,
        const unsigned* __restrict__ zt,
        const unsigned short* __restrict__ Bp1, const unsigned short* __restrict__ Bp2,
        const float* __restrict__ sh1, const float* __restrict__ sc2,
        const float* __restrict__ sh2,
        unsigned* __restrict__ hm, unsigned* __restrict__ ht, int M) {
    __shared__ unsigned short t_lds[128 * TS];   // 43008 B
    int tid = threadIdx.x;
    int w = tid >> 6, l = tid & 63;
    int rowg = w >> 1;
    int chh = w & 1;
    int ch = chh * 80;
    int kg = l >> 4;
    int lr = l & 15;
    int mbase = blockIdx.x * 128;

    int rr[4]; bool ok[4];
#pragma unroll
    for (int s = 0; s < 4; s++) { rr[s] = mbase + rowg * 16 + s * 32 + lr; ok[s] = rr[s] < M; }

    f32x4 acc[4][5] = {};
    // ---- stage 1: z @ W1 (A from PLANE layout) ----
    for (int ks = 0; ks < 5; ++ks) {
        union { bf16x8 v; uint4 u; } af[4];
        int pl = 2 * ks + (kg >> 1);
        int off = (kg & 1) * 4;
#pragma unroll
        for (int s = 0; s < 4; s++) {
            if (ks < 4) af[s].u = ok[s] ? *(const uint4*)(zm + (size_t)pl * PLANE + (size_t)rr[s] * 8 + off)
                                        : make_uint4(0, 0, 0, 0);
            else        af[s].u = make_uint4((kg == 0 && ok[s]) ? zt[rr[s]] : 0u, 0, 0, 0);
        }
        const unsigned short* bb = Bp1 + ((size_t)((ks * 10 + chh * 5) * 64 + l)) * 8;
#pragma unroll
        for (int f = 0; f < 5; ++f) {
            union { bf16x8 v; uint4 u; } bf;
            bf.u = *(const uint4*)(bb + (size_t)f * 512);
#pragma unroll
            for (int s = 0; s < 4; s++)
                acc[s][f] = __builtin_amdgcn_mfma_f32_16x16x32_bf16(af[s].v, bf.v, acc[s][f], 0, 0, 0);
        }
    }
    // epilogue1: t = relu(acc + b1) -> LDS
#pragma unroll
    for (int f = 0; f < 5; ++f) {
        int c = ch + lr + f * 16;
        float sh = sh1[c];
#pragma unroll
        for (int s = 0; s < 4; s++) {
            int rl = rowg * 16 + s * 32 + kg * 4;
#pragma unroll
            for (int j = 0; j < 4; ++j)
                t_lds[(rl + j) * TS + c] = f2bf(fmaxf(acc[s][f][j] + sh, 0.f));
        }
    }
    __syncthreads();
    // ---- stage 2: t @ W2 ----
#pragma unroll
    for (int s = 0; s < 4; s++)
#pragma unroll
        for (int f = 0; f < 5; ++f) acc[s][f] = (f32x4){0, 0, 0, 0};
    for (int ks = 0; ks < 5; ++ks) {
        union { bf16x8 v; uint4 u; } af[4];
#pragma unroll
        for (int s = 0; s < 4; s++)
            af[s].u = *(const uint4*)(t_lds + (size_t)(rowg * 16 + s * 32 + lr) * TS + ks * 32 + kg * 8);
        const unsigned short* bb = Bp2 + ((size_t)((ks * 10 + chh * 5) * 64 + l)) * 8;
#pragma unroll
        for (int f = 0; f < 5; ++f) {
            union { bf16x8 v; uint4 u; } bf;
            bf.u = *(const uint4*)(bb + (size_t)f * 512);
#pragma unroll
            for (int s = 0; s < 4; s++)
                acc[s][f] = __builtin_amdgcn_mfma_f32_16x16x32_bf16(af[s].v, bf.v, acc[s][f], 0, 0, 0);
        }
    }
    __syncthreads();   // stage-2 reads complete before overwrite
    // epilogue2: BN fold + relu -> LDS (overwrite)
#pragma unroll
    for (int f = 0; f < 5; ++f) {
        int c = ch + lr + f * 16;
        float sc = sc2[c], sh = sh2[c];
#pragma unroll
        for (int s = 0; s < 4; s++) {
            int rl = rowg * 16 + s * 32 + kg * 4;
#pragma unroll
            for (int j = 0; j < 4; ++j)
                t_lds[(rl + j) * TS + c] = f2bf(fmaxf(fmaf(acc[s][f][j], sc, sh), 0.f));
        }
    }
    __syncthreads();
    // copy-out to PLANE layout: per plane, 128 rows x 32B (coalesced 4KB)
#pragma unroll
    for (int pl = 0; pl < 8; ++pl) {
        int row = tid >> 1, half = tid & 1;
        int gr = mbase + row;
        if (gr < M) {
            u32x4 v = *(const u32x4*)(t_lds + (size_t)row * TS + pl * 16 + half * 8);
            __builtin_nontemporal_store(v,
                (u32x4*)(hm + (size_t)pl * PLANE + (size_t)gr * 8 + half * 4));
        }
    }
    if (tid < 128) {
        int row = tid;
        int gr = mbase + row;
        if (gr < M) {
            unsigned v = *(const unsigned*)(t_lds + (size_t)row * TS + 128);
            __builtin_nontemporal_store(v, &ht[gr]);
        }
    }
}

// ---------------------------------------------------------------------------
// Fused head: out = relu(h@Wh1+bh1) @ Wh2 + bh2   [N,2] fp32 (PLANE input)
// ---------------------------------------------------------------------------
__global__ __launch_bounds__(256) void k_head(const unsigned* __restrict__ hm,
        const unsigned* __restrict__ ht, const unsigned short* __restrict__ Bp8,
        const float* __restrict__ sh1, const float* __restrict__ Wh2p,
        const float* __restrict__ bh2, float* __restrict__ out, int M) {
    __shared__ float red[64][2][2];
    int tid = threadIdx.x;
    int w = tid >> 6, l = tid & 63;
    int rowg = w >> 1;
    int chh = w & 1;
    int ch = chh * 80;
    int kg = l >> 4;
    int lr = l & 15;
    int mbase = blockIdx.x * 64;
    int r0 = mbase + rowg * 16 + lr;
    int r1 = r0 + 32;
    bool ok0 = r0 < M, ok1 = r1 < M;

    f32x4 acc0[5] = {}, acc1[5] = {};
#pragma unroll
    for (int ks = 0; ks < 5; ++ks) {
        union { bf16x8 v; uint4 u; } af0, af1;
        int pl = 2 * ks + (kg >> 1);
        int off = (kg & 1) * 4;
        if (ks < 4) {
            af0.u = ok0 ? *(const uint4*)(hm + (size_t)pl * PLANE + (size_t)r0 * 8 + off)
                        : make_uint4(0, 0, 0, 0);
            af1.u = ok1 ? *(const uint4*)(hm + (size_t)pl * PLANE + (size_t)r1 * 8 + off)
                        : make_uint4(0, 0, 0, 0);
        } else {
            af0.u = make_uint4((kg == 0 && ok0) ? ht[r0] : 0u, 0, 0, 0);
            af1.u = make_uint4((kg == 0 && ok1) ? ht[r1] : 0u, 0, 0, 0);
        }
        const unsigned short* bb = Bp8 + ((size_t)((ks * 10 + chh * 5) * 64 + l)) * 8;
#pragma unroll
        for (int f = 0; f < 5; ++f) {
            union { bf16x8 v; uint4 u; } bf;
            bf.u = *(const uint4*)(bb + (size_t)f * 512);
            acc0[f] = __builtin_amdgcn_mfma_f32_16x16x32_bf16(af0.v, bf.v, acc0[f], 0, 0, 0);
            acc1[f] = __builtin_amdgcn_mfma_f32_16x16x32_bf16(af1.v, bf.v, acc1[f], 0, 0, 0);
        }
    }
    float p0[4][2] = {}, p1[4][2] = {};
#pragma unroll
    for (int f = 0; f < 5; ++f) {
        int c = ch + lr + f * 16;
        float sh = sh1[c];
        float w0 = Wh2p[c * 2], w1 = Wh2p[c * 2 + 1];
#pragma unroll
        for (int j = 0; j < 4; ++j) {
            float u0 = fmaxf(acc0[f][j] + sh, 0.f);
            float u1 = fmaxf(acc1[f][j] + sh, 0.f);
            p0[j][0] = fmaf(u0, w0, p0[j][0]); p0[j][1] = fmaf(u0, w1, p0[j][1]);
            p1[j][0] = fmaf(u1, w0, p1[j][0]); p1[j][1] = fmaf(u1, w1, p1[j][1]);
        }
    }
#pragma unroll
    for (int m = 1; m < 16; m <<= 1) {
#pragma unroll
        for (int j = 0; j < 4; ++j) {
#pragma unroll
            for (int k = 0; k < 2; ++k) {
                p0[j][k] += __shfl_xor(p0[j][k], m, 64);
                p1[j][k] += __shfl_xor(p1[j][k], m, 64);
            }
        }
    }
    if (lr == 0) {
        int rl = rowg * 16 + kg * 4;
#pragma unroll
        for (int j = 0; j < 4; ++j) {
            red[rl + j][chh][0] = p0[j][0];      red[rl + j][chh][1] = p0[j][1];
            red[rl + 32 + j][chh][0] = p1[j][0]; red[rl + 32 + j][chh][1] = p1[j][1];
        }
    }
    __syncthreads();
    if (tid < 128) {
        int r = tid >> 1, k = tid & 1;
        int gr = mbase + r;
        if (gr < M) out[gr * 2 + k] = red[r][0][k] + red[r][1][k] + bh2[k];
    }
}

// ---------------------------------------------------------------------------
extern "C" void kernel_launch(void* const* d_in, const int* in_sizes, int n_in,
                              void* d_out, int out_size, void* d_ws, size_t ws_size,
                              hipStream_t stream) {
    const int* x_type  = (const int*)d_in[0];
    const int* x_tok   = (const int*)d_in[1];
    const float* x_small = (const float*)d_in[2];
    const int* e_src   = (const int*)d_in[3];
    const int* e_dst   = e_src + E_EDGES;
    const int* e_type  = (const int*)d_in[4];
    const float* W1    = (const float*)d_in[6];
    const float* b1    = (const float*)d_in[7];
    const float* W2    = (const float*)d_in[8];
    const float* b2    = (const float*)d_in[9];
    const float* gamma = (const float*)d_in[10];
    const float* beta  = (const float*)d_in[11];
    const float* rmean = (const float*)d_in[12];
    const float* rvar  = (const float*)d_in[13];
    const float* Wh1   = (const float*)d_in[14];
    const float* bh1   = (const float*)d_in[15];
    const float* Wh2   = (const float*)d_in[16];
    const float* bh2   = (const float*)d_in[17];
    float* out = (float*)d_out;

    char* ws = (char*)d_ws;
    size_t o = 0;
    auto take = [&](size_t bytes) -> void* {
        void* p = ws + o;
        o = (o + bytes + 255) & ~(size_t)255;
        return p;
    };
    const size_t HM_BUF = (size_t)N_NODES * 64 * sizeof(unsigned);  // 12.8 MB
    unsigned* hmA = (unsigned*)take(HM_BUF);   // h (layer state, PLANE layout)
    unsigned* hmZ = (unsigned*)take(HM_BUF);   // z (PLANE layout)
    unsigned* htA = (unsigned*)take((size_t)N_NODES * 4);
    unsigned* htZ = (unsigned*)take((size_t)N_NODES * 4);
    unsigned* htM0 = (unsigned*)take((size_t)N_NODES * 4);
    unsigned short* xtk = (unsigned short*)take((size_t)N_NODES * 2);
    unsigned short* Bp = (unsigned short*)take((size_t)9 * 50 * 64 * 8 * sizeof(unsigned short));
    float* Wh2p = (float*)take((size_t)CP * 2 * sizeof(float));
    float* ss   = (float*)take((size_t)9 * 2 * CP * sizeof(float));
    float4* cntf  = (float4*)take((size_t)N_NODES * sizeof(float4));
    int* indeg    = (int*)take((size_t)N_NODES * sizeof(int));
    unsigned short* rank16 = (unsigned short*)take((size_t)E_EDGES * 2);
    int* rowstart = (int*)take((size_t)(N_NODES + 1) * sizeof(int));
    int* bsum     = (int*)take(64 * sizeof(int));
    int* csr      = (int*)take((size_t)E_EDGES * sizeof(int));
    (void)ws_size; (void)in_sizes; (void)n_in; (void)out_size;

    const int NB_SCAN = (N_NODES + 1023) / 1024;  // 49

    // mega prep: weights, epilogue constants, tail feats + xtk, zero indeg
    k_prep<<<PREP_BLKS + FEAT_BLKS + ZERO_BLKS, 256, 0, stream>>>(
        W1, W2, Wh1, Wh2, b1, b2, gamma, beta, rmean, rvar, bh1,
        x_type, x_tok, x_small, Bp, Wh2p, ss, xtk, htA, htM0, indeg);

    // CSR by dst: rank via atomic return, fill without atomics
    k_indeg<<<(E_EDGES + 255) / 256, 256, 0, stream>>>(e_dst, indeg, rank16);
    k_scan1<<<NB_SCAN, 256, 0, stream>>>(indeg, rowstart, bsum);
    k_scan23<<<NB_SCAN, 256, 0, stream>>>(rowstart, bsum);
    k_fill<<<(E_EDGES + 255) / 256, 256, 0, stream>>>(e_src, e_dst, e_type, rank16,
                                                      rowstart, csr);

    // layers
    const int MLP_GRID = (N_NODES + 127) / 128;  // 391
    for (int l = 0; l < L_LAYERS; l++) {
        int g1 = 2 * l, g2 = 2 * l + 1;
        if (l == 0)
            k_spmm<true><<<TAIL_BLKS + L0_MAIN_BLKS, 256, 0, stream>>>(
                hmA, xtk, htM0, htA, rowstart, csr, cntf, hmZ, htZ);
        else
            k_spmm<false><<<TAIL_BLKS + DENSE_MAIN_BLKS, 256, 0, stream>>>(
                hmA, xtk, htA, htA, rowstart, csr, cntf, hmZ, htZ);
        k_mlp<<<MLP_GRID, 256, 0, stream>>>(hmZ, htZ,
            Bp + (size_t)g1 * 25600, Bp + (size_t)g2 * 25600,
            ss + (size_t)(2 * g1 + 1) * CP,
            ss + (size_t)(2 * g2) * CP, ss + (size_t)(2 * g2 + 1) * CP,
            hmA, htA, N_NODES);
    }

    // fused head
    k_head<<<(N_NODES + 63) / 64, 256, 0, stream>>>(hmA, htA, Bp + (size_t)8 * 25600,
        ss + (size_t)(2 * 8 + 1) * CP, Wh2p, bh2, out, N_NODES);
}

// Round 13
// 296.682 us; speedup vs baseline: 2.0398x; 2.0398x over previous
//
#include <hip/hip_runtime.h>
#include <hip/hip_bf16.h>

// Problem constants (match reference setup_inputs)
#define N_NODES 50000
#define E_EDGES 600000
#define C_CH    130
#define CP      160      // padded channel width for weights/frags
#define L_LAYERS 4
#define BN_EPS  1e-5f
#define TS      168      // LDS t-tile stride (ushorts)

#define MAIN_BLKS 12500              // (N+3)/4, wave-per-node gather blocks
#define TAIL_BLKS 196                // (N+255)/256 tail-plane blocks (run FIRST)

// prep block ranges: packB(45, LDS-staged) | padWh2(1) | ss(9) | feat(196) | zero(49)
#define PACKB_BLKS 45
#define PREP_BLKS  (PACKB_BLKS + 1 + 9)   // 55
#define FEAT_BLKS  196
#define ZERO_BLKS  49

typedef __bf16 bf16x8 __attribute__((ext_vector_type(8)));
typedef float  f32x4  __attribute__((ext_vector_type(4)));
typedef unsigned u32x4 __attribute__((ext_vector_type(4)));

// fp32 -> bf16 RNE
__device__ __forceinline__ unsigned short f2bf(float f) {
    unsigned u = __float_as_uint(f);
    unsigned r = (u + 0x7FFFu + ((u >> 16) & 1u)) >> 16;
    return (unsigned short)r;
}
__device__ __forceinline__ unsigned packbf(float lo, float hi) {
    return (unsigned)f2bf(lo) | ((unsigned)f2bf(hi) << 16);
}
__device__ __forceinline__ float bflo(unsigned d) { return __uint_as_float(d << 16); }
__device__ __forceinline__ float bfhi(unsigned d) { return __uint_as_float(d & 0xFFFF0000u); }

// ---------------------------------------------------------------------------
// Mega prep: [0,45) packB LDS-staged | 45 padWh2 | [46,55) ss |
//            [55,251) tail feats + xtk | [251,300) zero indeg
// ---------------------------------------------------------------------------
__global__ __launch_bounds__(256) void k_prep(
        const float* __restrict__ W1, const float* __restrict__ W2,
        const float* __restrict__ Wh1, const float* __restrict__ Wh2,
        const float* __restrict__ b1, const float* __restrict__ b2,
        const float* __restrict__ gamma, const float* __restrict__ beta,
        const float* __restrict__ rmean, const float* __restrict__ rvar,
        const float* __restrict__ bh1,
        const int* __restrict__ xt, const int* __restrict__ xk,
        const float* __restrict__ xs,
        unsigned short* __restrict__ Bp, float* __restrict__ Wh2p,
        float* __restrict__ ss, unsigned short* __restrict__ xtk,
        unsigned* __restrict__ ht, unsigned* __restrict__ htm,
        int* __restrict__ indeg) {
    int blk = blockIdx.x;
    int tid = threadIdx.x;
    if (blk < PACKB_BLKS) {
        __shared__ float wlds[32][132];          // +2 pad
        int g = blk / 5, ks = blk - g * 5;
        const float* W;
        if (g < 8) W = (g & 1) ? (W2 + (size_t)(g >> 1) * C_CH * C_CH)
                               : (W1 + (size_t)(g >> 1) * C_CH * C_CH);
        else       W = Wh1;
        for (int i = tid; i < 32 * C_CH; i += 256) {
            int kk = i / C_CH, c = i - kk * C_CH;
            int k = ks * 32 + kk;
            wlds[kk][c] = (k < C_CH) ? W[(size_t)k * C_CH + c] : 0.f;
        }
        __syncthreads();
        for (int q = tid; q < 640; q += 256) {   // 10 frags x 64 lanes
            int f = q >> 6, l = q & 63;
            int kg = l >> 4, c = f * 16 + (l & 15);
            union { unsigned short s[8]; uint4 u; } out;
#pragma unroll
            for (int j = 0; j < 8; j++) {
                float v = (c < C_CH) ? wlds[kg * 8 + j][c] : 0.f;
                out.s[j] = f2bf(v);
            }
            *(uint4*)(Bp + ((size_t)((g * 50 + ks * 10 + f) * 64 + l) * 8)) = out.u;
        }
        return;
    }
    if (blk == PACKB_BLKS) {
        for (int i = tid; i < CP * 2; i += 256) {
            int r = i >> 1, c = i & 1;
            Wh2p[i] = (r < C_CH) ? Wh2[r * 2 + c] : 0.f;
        }
        return;
    }
    if (blk < PREP_BLKS) {
        int g = blk - (PACKB_BLKS + 1);      // 0..8
        int c = tid;
        if (c >= CP) return;
        float scale = 1.f, shift = 0.f;
        if (g < 2 * L_LAYERS) {
            int l = g >> 1;
            if ((g & 1) == 0) {
                if (c < C_CH) shift = b1[l * C_CH + c];
            } else if (c < C_CH) {
                float s = gamma[l * C_CH + c] * rsqrtf(rvar[l * C_CH + c] + BN_EPS);
                scale = s;
                shift = (b2[l * C_CH + c] - rmean[l * C_CH + c]) * s + beta[l * C_CH + c];
            }
        } else {
            if (c < C_CH) shift = bh1[c];
        }
        ss[(g * 2 + 0) * CP + c] = scale;
        ss[(g * 2 + 1) * CP + c] = shift;
        return;
    }
    if (blk < PREP_BLKS + FEAT_BLKS) {
        int n = (blk - PREP_BLKS) * 256 + tid;
        if (n < N_NODES) {
            int t = xt[n];                       // 0..31
            int k = xk[n]; k = k < 0 ? 0 : (k > 95 ? 95 : k);
            xtk[n] = (unsigned short)(t | (k << 5));
            float a = xs[2 * n], b = xs[2 * n + 1];
            ht[n]  = packbf(a, b);
            htm[n] = packbf(fmaxf(a, 0.f), fmaxf(b, 0.f));
        }
        return;
    }
    {
        int slot = (blk - PREP_BLKS - FEAT_BLKS) * 256 + tid;
        if (slot < N_NODES / 4)
            ((int4*)indeg)[slot] = make_int4(0, 0, 0, 0);
    }
}

// ---------------------------------------------------------------------------
// CSR-by-dst build: rank from atomic return; fill without atomics
// ---------------------------------------------------------------------------
__global__ void k_indeg(const int* __restrict__ dst, int* __restrict__ indeg,
                        unsigned short* __restrict__ rank16) {
    int e = blockIdx.x * blockDim.x + threadIdx.x;
    if (e >= E_EDGES) return;
    int r = atomicAdd(&indeg[dst[e]], 1);
    __builtin_nontemporal_store((unsigned short)r, &rank16[e]);
}

__global__ void k_scan1(const int* __restrict__ indeg, int* __restrict__ localscan,
                        int* __restrict__ bsum) {
    __shared__ int lds[256];
    int tid = threadIdx.x;
    int base = blockIdx.x * 1024 + tid * 4;
    int v[4]; int s = 0;
#pragma unroll
    for (int r = 0; r < 4; r++) {
        int i = base + r;
        v[r] = (i < N_NODES) ? indeg[i] : 0;
        s += v[r];
    }
    lds[tid] = s;
    __syncthreads();
    for (int off = 1; off < 256; off <<= 1) {
        int x = (tid >= off) ? lds[tid - off] : 0;
        __syncthreads();
        lds[tid] += x;
        __syncthreads();
    }
    int excl = lds[tid] - s;
    int w = excl;
#pragma unroll
    for (int r = 0; r < 4; r++) {
        int i = base + r;
        if (i < N_NODES) localscan[i] = w;
        w += v[r];
    }
    if (tid == 255) bsum[blockIdx.x] = lds[255];
}

// merged scan2+scan3: each block wave-reduces its exclusive block offset
__global__ void k_scan23(int* __restrict__ rowstart, const int* __restrict__ bsum) {
    __shared__ int offs;
    int tid = threadIdx.x;
    int b = blockIdx.x;
    if (tid < 64) {
        int v = (tid < b) ? bsum[tid] : 0;
#pragma unroll
        for (int m = 1; m < 64; m <<= 1) v += __shfl_xor(v, m, 64);
        if (tid == 0) offs = v;
    }
    __syncthreads();
    int add = offs;
    int base = b * 1024 + tid * 4;
#pragma unroll
    for (int r = 0; r < 4; r++) {
        int i = base + r;
        if (i < N_NODES) rowstart[i] += add;
    }
    if (b == 0 && tid == 0) rowstart[N_NODES] = E_EDGES;
}

// csr[slot] = src | et<<16 (L0 consumer); csr16[slot] = src (dense/tail)
__global__ void k_fill(const int* __restrict__ src, const int* __restrict__ dst,
                       const int* __restrict__ et,
                       const unsigned short* __restrict__ rank16,
                       const int* __restrict__ rowstart, int* __restrict__ csr,
                       unsigned short* __restrict__ csr16) {
    int e = blockIdx.x * blockDim.x + threadIdx.x;
    if (e >= E_EDGES) return;
    int d = dst[e];
    int slot = rowstart[d] + (int)rank16[e];
    int s = src[e];
    __builtin_nontemporal_store(s | (et[e] << 16), &csr[slot]);
    __builtin_nontemporal_store((unsigned short)s, &csr16[slot]);
}

// ---------------------------------------------------------------------------
// Aggregation. blocks [0,TAIL_BLKS): tail plane (node/thread).
// blocks [TAIL_BLKS, +MAIN_BLKS): main plane, wave per node.
// L0: index-histogram gather (2B/edge); persists cntf[n].
// L>=1: 4-slot dense gather; src via ushort csr16; cntf hoisted.
// ---------------------------------------------------------------------------
template<bool L0>
__global__ __launch_bounds__(256) void k_spmm(const unsigned* __restrict__ hm,
                                              const unsigned short* __restrict__ xtk,
                                              const unsigned* __restrict__ tmsg,
                                              const unsigned* __restrict__ ht,
                                              const int* __restrict__ rowstart,
                                              const int* __restrict__ csr,
                                              const unsigned short* __restrict__ csr16,
                                              float4* __restrict__ cntf,
                                              unsigned* __restrict__ zm,
                                              unsigned* __restrict__ zt) {
    int b = blockIdx.x;
    if (b < TAIL_BLKS) {
        int n = b * 256 + threadIdx.x;
        if (n >= N_NODES) return;
        unsigned hn = ht[n];
        float a0 = bflo(hn), a1 = bfhi(hn);
        int rs = rowstart[n], re = rowstart[n + 1];
        for (int e = rs; e < re; ++e) {
            unsigned q = tmsg[csr16[e]];
            a0 += bflo(q); a1 += bfhi(q);
        }
        __builtin_nontemporal_store(packbf(a0, a1), &zt[n]);
        return;
    }
    int wave = threadIdx.x >> 6;
    int lane = threadIdx.x & 63;
    int n = (b - TAIL_BLKS) * 4 + wave;
    if (n >= N_NODES) return;
    int rs = rowstart[n], re = rowstart[n + 1];

    if (L0) {
        int c0 = 2 * lane, c1 = c0 + 1;
        int ce0 = 0, ce1 = 0, ce2 = 0;
        int xv_s = xtk[n];
        int ts = xv_s & 31, ks = 32 + (xv_s >> 5);
        int ia0 = (ts == c0) + (ks == c0);
        int ia1 = (ts == c1) + (ks == c1);
        for (int e = rs; e < re; e += 16) {
            unsigned p[16]; int xv[16];
#pragma unroll
            for (int r = 0; r < 16; r++) {
                int ee = e + r; ee = (ee < re) ? ee : (re - 1);
                p[r] = (unsigned)csr[ee];
            }
#pragma unroll
            for (int r = 0; r < 16; r++)
                xv[r] = xtk[p[r] & 0xFFFFu];
#pragma unroll
            for (int r = 0; r < 16; r++) {
                if (e + r < re) {
                    int t = xv[r] & 31, k = 32 + (xv[r] >> 5);
                    ia0 += (t == c0) + (k == c0);
                    ia1 += (t == c1) + (k == c1);
                    unsigned et = p[r] >> 16;
                    ce0 += (et == 0); ce1 += (et == 1); ce2 += (et == 2);
                }
            }
        }
        float a0 = (float)ia0, a1 = (float)ia1;
        if (lane == 0) {
            cntf[n] = make_float4((float)ce0, (float)ce1, (float)ce2, 0.f);
            a0 += (float)ce0; a1 += (float)ce1;
        } else if (lane == 1) {
            a0 += (float)ce2;
        }
        __builtin_nontemporal_store(packbf(a0, a1), &zm[(size_t)n * 64 + lane]);
    } else {
        int slot = lane >> 4;        // 0..3: edge subset e%4==slot
        int dw   = lane & 15;        // owns dwords 4dw..4dw+3 (16B)
        float a[8] = {};
        for (int e = rs; e < re; e += 32) {
            unsigned p[8];
            uint4 d[8];
#pragma unroll
            for (int r = 0; r < 8; r++) {
                int ee = e + 4 * r + slot;
                ee = (ee < re) ? ee : (re - 1);
                p[r] = csr16[ee];
            }
#pragma unroll
            for (int r = 0; r < 8; r++)
                d[r] = *(const uint4*)(hm + (size_t)p[r] * 64 + dw * 4);
#pragma unroll
            for (int r = 0; r < 8; r++) {
                if (e + 4 * r + slot < re) {
                    a[0] += bflo(d[r].x); a[1] += bfhi(d[r].x);
                    a[2] += bflo(d[r].y); a[3] += bfhi(d[r].y);
                    a[4] += bflo(d[r].z); a[5] += bfhi(d[r].z);
                    a[6] += bflo(d[r].w); a[7] += bfhi(d[r].w);
                }
            }
        }
#pragma unroll
        for (int m = 16; m <= 32; m <<= 1) {
#pragma unroll
            for (int j = 0; j < 8; j++) a[j] += __shfl_xor(a[j], m, 64);
        }
        if (slot == 0) {
            uint4 hn = *(const uint4*)(hm + (size_t)n * 64 + dw * 4);
            a[0] += bflo(hn.x); a[1] += bfhi(hn.x);
            a[2] += bflo(hn.y); a[3] += bfhi(hn.y);
            a[4] += bflo(hn.z); a[5] += bfhi(hn.z);
            a[6] += bflo(hn.w); a[7] += bfhi(hn.w);
            if (dw == 0) {
                float4 c = cntf[n];
                a[0] += c.x; a[1] += c.y; a[2] += c.z;
            }
            u32x4 o;
            o.x = packbf(a[0], a[1]); o.y = packbf(a[2], a[3]);
            o.z = packbf(a[4], a[5]); o.w = packbf(a[6], a[7]);
            __builtin_nontemporal_store(o, (u32x4*)(zm + (size_t)n * 64 + dw * 4));
        }
    }
}

// ---------------------------------------------------------------------------
// Fused MLP layer, 128-row blocks: h_out = relu(BN(relu(z@W1+b1)@W2+b2))
// Output routed through t_lds -> coalesced nt uint4 stores.
// ---------------------------------------------------------------------------
__global__ __launch_bounds__(256) void k_mlp(const unsigned* __restrict__ zm,
        const unsigned* __restrict__ zt,
        const unsigned short* __restrict__ Bp1, const unsigned short* __restrict__ Bp2,
        const float* __restrict__ sh1, const float* __restrict__ sc2,
        const float* __restrict__ sh2,
        unsigned* __restrict__ hm, unsigned* __restrict__ ht, int M) {
    __shared__ unsigned short t_lds[128 * TS];   // 43008 B
    int tid = threadIdx.x;
    int w = tid >> 6, l = tid & 63;
    int rowg = w >> 1;
    int chh = w & 1;
    int ch = chh * 80;
    int kg = l >> 4;
    int lr = l & 15;
    int mbase = blockIdx.x * 128;

    int rr[4]; bool ok[4];
#pragma unroll
    for (int s = 0; s < 4; s++) { rr[s] = mbase + rowg * 16 + s * 32 + lr; ok[s] = rr[s] < M; }

    f32x4 acc[4][5] = {};
    // ---- stage 1: z @ W1 ----
    for (int ks = 0; ks < 5; ++ks) {
        union { bf16x8 v; uint4 u; } af[4];
#pragma unroll
        for (int s = 0; s < 4; s++) {
            if (ks < 4) af[s].u = ok[s] ? *(const uint4*)(zm + (size_t)rr[s] * 64 + kg * 4 + ks * 16)
                                        : make_uint4(0, 0, 0, 0);
            else        af[s].u = make_uint4((kg == 0 && ok[s]) ? zt[rr[s]] : 0u, 0, 0, 0);
        }
        const unsigned short* bb = Bp1 + ((size_t)((ks * 10 + chh * 5) * 64 + l)) * 8;
#pragma unroll
        for (int f = 0; f < 5; ++f) {
            union { bf16x8 v; uint4 u; } bf;
            bf.u = *(const uint4*)(bb + (size_t)f * 512);
#pragma unroll
            for (int s = 0; s < 4; s++)
                acc[s][f] = __builtin_amdgcn_mfma_f32_16x16x32_bf16(af[s].v, bf.v, acc[s][f], 0, 0, 0);
        }
    }
    // epilogue1: t = relu(acc + b1) -> LDS
#pragma unroll
    for (int f = 0; f < 5; ++f) {
        int c = ch + lr + f * 16;
        float sh = sh1[c];
#pragma unroll
        for (int s = 0; s < 4; s++) {
            int rl = rowg * 16 + s * 32 + kg * 4;
#pragma unroll
            for (int j = 0; j < 4; ++j)
                t_lds[(rl + j) * TS + c] = f2bf(fmaxf(acc[s][f][j] + sh, 0.f));
        }
    }
    __syncthreads();
    // ---- stage 2: t @ W2 ----
#pragma unroll
    for (int s = 0; s < 4; s++)
#pragma unroll
        for (int f = 0; f < 5; ++f) acc[s][f] = (f32x4){0, 0, 0, 0};
    for (int ks = 0; ks < 5; ++ks) {
        union { bf16x8 v; uint4 u; } af[4];
#pragma unroll
        for (int s = 0; s < 4; s++)
            af[s].u = *(const uint4*)(t_lds + (size_t)(rowg * 16 + s * 32 + lr) * TS + ks * 32 + kg * 8);
        const unsigned short* bb = Bp2 + ((size_t)((ks * 10 + chh * 5) * 64 + l)) * 8;
#pragma unroll
        for (int f = 0; f < 5; ++f) {
            union { bf16x8 v; uint4 u; } bf;
            bf.u = *(const uint4*)(bb + (size_t)f * 512);
#pragma unroll
            for (int s = 0; s < 4; s++)
                acc[s][f] = __builtin_amdgcn_mfma_f32_16x16x32_bf16(af[s].v, bf.v, acc[s][f], 0, 0, 0);
        }
    }
    __syncthreads();   // stage-2 reads complete before overwrite
    // epilogue2: BN fold + relu -> LDS (overwrite)
#pragma unroll
    for (int f = 0; f < 5; ++f) {
        int c = ch + lr + f * 16;
        float sc = sc2[c], sh = sh2[c];
#pragma unroll
        for (int s = 0; s < 4; s++) {
            int rl = rowg * 16 + s * 32 + kg * 4;
#pragma unroll
            for (int j = 0; j < 4; ++j)
                t_lds[(rl + j) * TS + c] = f2bf(fmaxf(fmaf(acc[s][f][j], sc, sh), 0.f));
        }
    }
    __syncthreads();
    // coalesced copy-out: 128 rows x 16 uint4 (ch 0..127) + 128 dwords (ch 128/129)
#pragma unroll
    for (int r = 0; r < 9; ++r) {
        int q = tid + 256 * r;
        if (q < 2048) {
            int row = q >> 4;
            int u4 = q & 15;
            int gr = mbase + row;
            if (gr < M) {
                u32x4 v = *(const u32x4*)(t_lds + (size_t)row * TS + u4 * 8);
                __builtin_nontemporal_store(v, (u32x4*)(hm + (size_t)gr * 64 + u4 * 4));
            }
        } else if (q < 2048 + 128) {
            int row = q - 2048;
            int gr = mbase + row;
            if (gr < M) {
                unsigned v = *(const unsigned*)(t_lds + (size_t)row * TS + 128);
                __builtin_nontemporal_store(v, &ht[gr]);
            }
        }
    }
}

// ---------------------------------------------------------------------------
// Fused head: out = relu(h@Wh1+bh1) @ Wh2 + bh2   [N,2] fp32
// ---------------------------------------------------------------------------
__global__ __launch_bounds__(256) void k_head(const unsigned* __restrict__ hm,
        const unsigned* __restrict__ ht, const unsigned short* __restrict__ Bp8,
        const float* __restrict__ sh1, const float* __restrict__ Wh2p,
        const float* __restrict__ bh2, float* __restrict__ out, int M) {
    __shared__ float red[64][2][2];
    int tid = threadIdx.x;
    int w = tid >> 6, l = tid & 63;
    int rowg = w >> 1;
    int chh = w & 1;
    int ch = chh * 80;
    int kg = l >> 4;
    int lr = l & 15;
    int mbase = blockIdx.x * 64;
    int r0 = mbase + rowg * 16 + lr;
    int r1 = r0 + 32;
    bool ok0 = r0 < M, ok1 = r1 < M;

    f32x4 acc0[5] = {}, acc1[5] = {};
    const unsigned* a0p = hm + (size_t)r0 * 64 + kg * 4;
    const unsigned* a1p = hm + (size_t)r1 * 64 + kg * 4;
#pragma unroll
    for (int ks = 0; ks < 5; ++ks) {
        union { bf16x8 v; uint4 u; } af0, af1;
        if (ks < 4) {
            af0.u = ok0 ? *(const uint4*)(a0p + ks * 16) : make_uint4(0, 0, 0, 0);
            af1.u = ok1 ? *(const uint4*)(a1p + ks * 16) : make_uint4(0, 0, 0, 0);
        } else {
            af0.u = make_uint4((kg == 0 && ok0) ? ht[r0] : 0u, 0, 0, 0);
            af1.u = make_uint4((kg == 0 && ok1) ? ht[r1] : 0u, 0, 0, 0);
        }
        const unsigned short* bb = Bp8 + ((size_t)((ks * 10 + chh * 5) * 64 + l)) * 8;
#pragma unroll
        for (int f = 0; f < 5; ++f) {
            union { bf16x8 v; uint4 u; } bf;
            bf.u = *(const uint4*)(bb + (size_t)f * 512);
            acc0[f] = __builtin_amdgcn_mfma_f32_16x16x32_bf16(af0.v, bf.v, acc0[f], 0, 0, 0);
            acc1[f] = __builtin_amdgcn_mfma_f32_16x16x32_bf16(af1.v, bf.v, acc1[f], 0, 0, 0);
        }
    }
    float p0[4][2] = {}, p1[4][2] = {};
#pragma unroll
    for (int f = 0; f < 5; ++f) {
        int c = ch + lr + f * 16;
        float sh = sh1[c];
        float w0 = Wh2p[c * 2], w1 = Wh2p[c * 2 + 1];
#pragma unroll
        for (int j = 0; j < 4; ++j) {
            float u0 = fmaxf(acc0[f][j] + sh, 0.f);
            float u1 = fmaxf(acc1[f][j] + sh, 0.f);
            p0[j][0] = fmaf(u0, w0, p0[j][0]); p0[j][1] = fmaf(u0, w1, p0[j][1]);
            p1[j][0] = fmaf(u1, w0, p1[j][0]); p1[j][1] = fmaf(u1, w1, p1[j][1]);
        }
    }
#pragma unroll
    for (int m = 1; m < 16; m <<= 1) {
#pragma unroll
        for (int j = 0; j < 4; ++j) {
#pragma unroll
            for (int k = 0; k < 2; ++k) {
                p0[j][k] += __shfl_xor(p0[j][k], m, 64);
                p1[j][k] += __shfl_xor(p1[j][k], m, 64);
            }
        }
    }
    if (lr == 0) {
        int rl = rowg * 16 + kg * 4;
#pragma unroll
        for (int j = 0; j < 4; ++j) {
            red[rl + j][chh][0] = p0[j][0];      red[rl + j][chh][1] = p0[j][1];
            red[rl + 32 + j][chh][0] = p1[j][0]; red[rl + 32 + j][chh][1] = p1[j][1];
        }
    }
    __syncthreads();
    if (tid < 128) {
        int r = tid >> 1, k = tid & 1;
        int gr = mbase + r;
        if (gr < M) out[gr * 2 + k] = red[r][0][k] + red[r][1][k] + bh2[k];
    }
}

// ---------------------------------------------------------------------------
extern "C" void kernel_launch(void* const* d_in, const int* in_sizes, int n_in,
                              void* d_out, int out_size, void* d_ws, size_t ws_size,
                              hipStream_t stream) {
    const int* x_type  = (const int*)d_in[0];
    const int* x_tok   = (const int*)d_in[1];
    const float* x_small = (const float*)d_in[2];
    const int* e_src   = (const int*)d_in[3];
    const int* e_dst   = e_src + E_EDGES;
    const int* e_type  = (const int*)d_in[4];
    const float* W1    = (const float*)d_in[6];
    const float* b1    = (const float*)d_in[7];
    const float* W2    = (const float*)d_in[8];
    const float* b2    = (const float*)d_in[9];
    const float* gamma = (const float*)d_in[10];
    const float* beta  = (const float*)d_in[11];
    const float* rmean = (const float*)d_in[12];
    const float* rvar  = (const float*)d_in[13];
    const float* Wh1   = (const float*)d_in[14];
    const float* bh1   = (const float*)d_in[15];
    const float* Wh2   = (const float*)d_in[16];
    const float* bh2   = (const float*)d_in[17];
    float* out = (float*)d_out;

    char* ws = (char*)d_ws;
    size_t o = 0;
    auto take = [&](size_t bytes) -> void* {
        void* p = ws + o;
        o = (o + bytes + 255) & ~(size_t)255;
        return p;
    };
    const size_t HM_BUF = (size_t)N_NODES * 64 * sizeof(unsigned);  // 12.8 MB
    unsigned* hmA = (unsigned*)take(HM_BUF);   // h (layer state)
    unsigned* hmZ = (unsigned*)take(HM_BUF);   // z
    unsigned* htA = (unsigned*)take((size_t)N_NODES * 4);
    unsigned* htZ = (unsigned*)take((size_t)N_NODES * 4);
    unsigned* htM0 = (unsigned*)take((size_t)N_NODES * 4);
    unsigned short* xtk = (unsigned short*)take((size_t)N_NODES * 2);
    unsigned short* Bp = (unsigned short*)take((size_t)9 * 50 * 64 * 8 * sizeof(unsigned short));
    float* Wh2p = (float*)take((size_t)CP * 2 * sizeof(float));
    float* ss   = (float*)take((size_t)9 * 2 * CP * sizeof(float));
    float4* cntf  = (float4*)take((size_t)N_NODES * sizeof(float4));
    int* indeg    = (int*)take((size_t)N_NODES * sizeof(int));
    unsigned short* rank16 = (unsigned short*)take((size_t)E_EDGES * 2);
    int* rowstart = (int*)take((size_t)(N_NODES + 1) * sizeof(int));
    int* bsum     = (int*)take(64 * sizeof(int));
    int* csr      = (int*)take((size_t)E_EDGES * sizeof(int));
    unsigned short* csr16 = (unsigned short*)take((size_t)E_EDGES * 2);
    (void)ws_size; (void)in_sizes; (void)n_in; (void)out_size;

    const int NB_SCAN = (N_NODES + 1023) / 1024;  // 49

    // mega prep: weights, epilogue constants, tail feats + xtk, zero indeg
    k_prep<<<PREP_BLKS + FEAT_BLKS + ZERO_BLKS, 256, 0, stream>>>(
        W1, W2, Wh1, Wh2, b1, b2, gamma, beta, rmean, rvar, bh1,
        x_type, x_tok, x_small, Bp, Wh2p, ss, xtk, htA, htM0, indeg);

    // CSR by dst: rank via atomic return, fill without atomics
    k_indeg<<<(E_EDGES + 255) / 256, 256, 0, stream>>>(e_dst, indeg, rank16);
    k_scan1<<<NB_SCAN, 256, 0, stream>>>(indeg, rowstart, bsum);
    k_scan23<<<NB_SCAN, 256, 0, stream>>>(rowstart, bsum);
    k_fill<<<(E_EDGES + 255) / 256, 256, 0, stream>>>(e_src, e_dst, e_type, rank16,
                                                      rowstart, csr, csr16);

    // layers
    const int SPMM_GRID = TAIL_BLKS + MAIN_BLKS;
    const int MLP_GRID = (N_NODES + 127) / 128;  // 391
    for (int l = 0; l < L_LAYERS; l++) {
        int g1 = 2 * l, g2 = 2 * l + 1;
        if (l == 0)
            k_spmm<true><<<SPMM_GRID, 256, 0, stream>>>(hmA, xtk, htM0, htA,
                rowstart, csr, csr16, cntf, hmZ, htZ);
        else
            k_spmm<false><<<SPMM_GRID, 256, 0, stream>>>(hmA, xtk, htA, htA,
                rowstart, csr, csr16, cntf, hmZ, htZ);
        k_mlp<<<MLP_GRID, 256, 0, stream>>>(hmZ, htZ,
            Bp + (size_t)g1 * 25600, Bp + (size_t)g2 * 25600,
            ss + (size_t)(2 * g1 + 1) * CP,
            ss + (size_t)(2 * g2) * CP, ss + (size_t)(2 * g2 + 1) * CP,
            hmA, htA, N_NODES);
    }

    // fused head
    k_head<<<(N_NODES + 63) / 64, 256, 0, stream>>>(hmA, htA, Bp + (size_t)8 * 25600,
        ss + (size_t)(2 * 8 + 1) * CP, Wh2p, bh2, out, N_NODES);
}

// Round 14
// 275.122 us; speedup vs baseline: 2.1997x; 1.0784x over previous
//
#include <hip/hip_runtime.h>
#include <hip/hip_bf16.h>

// Problem constants (match reference setup_inputs)
#define N_NODES 50000
#define E_EDGES 600000
#define C_CH    130
#define CP      160      // padded channel width for weights/frags
#define L_LAYERS 4
#define BN_EPS  1e-5f
#define TS      168      // LDS t-tile stride (ushorts)

#define MAIN_BLKS 12500              // (N+3)/4, wave-per-node gather blocks
#define TAIL_BLKS 196                // (N+255)/256 tail-plane blocks (run FIRST)

// prep block ranges: packB(45, LDS-staged) | padWh2(1) | ss(9) | feat(196) | zero(49)
#define PACKB_BLKS 45
#define PREP_BLKS  (PACKB_BLKS + 1 + 9)   // 55
#define FEAT_BLKS  196
#define ZERO_BLKS  49

typedef __bf16 bf16x8 __attribute__((ext_vector_type(8)));
typedef float  f32x4  __attribute__((ext_vector_type(4)));
typedef unsigned u32x4 __attribute__((ext_vector_type(4)));

// fp32 -> bf16 RNE
__device__ __forceinline__ unsigned short f2bf(float f) {
    unsigned u = __float_as_uint(f);
    unsigned r = (u + 0x7FFFu + ((u >> 16) & 1u)) >> 16;
    return (unsigned short)r;
}
__device__ __forceinline__ unsigned packbf(float lo, float hi) {
    return (unsigned)f2bf(lo) | ((unsigned)f2bf(hi) << 16);
}
__device__ __forceinline__ float bflo(unsigned d) { return __uint_as_float(d << 16); }
__device__ __forceinline__ float bfhi(unsigned d) { return __uint_as_float(d & 0xFFFF0000u); }

// ---------------------------------------------------------------------------
// Mega prep: [0,45) packB LDS-staged | 45 padWh2 | [46,55) ss |
//            [55,251) tail feats + xtk | [251,300) zero indeg
// ---------------------------------------------------------------------------
__global__ __launch_bounds__(256) void k_prep(
        const float* __restrict__ W1, const float* __restrict__ W2,
        const float* __restrict__ Wh1, const float* __restrict__ Wh2,
        const float* __restrict__ b1, const float* __restrict__ b2,
        const float* __restrict__ gamma, const float* __restrict__ beta,
        const float* __restrict__ rmean, const float* __restrict__ rvar,
        const float* __restrict__ bh1,
        const int* __restrict__ xt, const int* __restrict__ xk,
        const float* __restrict__ xs,
        unsigned short* __restrict__ Bp, float* __restrict__ Wh2p,
        float* __restrict__ ss, unsigned short* __restrict__ xtk,
        unsigned* __restrict__ ht, unsigned* __restrict__ htm,
        int* __restrict__ indeg) {
    int blk = blockIdx.x;
    int tid = threadIdx.x;
    if (blk < PACKB_BLKS) {
        __shared__ float wlds[32][132];          // +2 pad
        int g = blk / 5, ks = blk - g * 5;
        const float* W;
        if (g < 8) W = (g & 1) ? (W2 + (size_t)(g >> 1) * C_CH * C_CH)
                               : (W1 + (size_t)(g >> 1) * C_CH * C_CH);
        else       W = Wh1;
        for (int i = tid; i < 32 * C_CH; i += 256) {
            int kk = i / C_CH, c = i - kk * C_CH;
            int k = ks * 32 + kk;
            wlds[kk][c] = (k < C_CH) ? W[(size_t)k * C_CH + c] : 0.f;
        }
        __syncthreads();
        for (int q = tid; q < 640; q += 256) {   // 10 frags x 64 lanes
            int f = q >> 6, l = q & 63;
            int kg = l >> 4, c = f * 16 + (l & 15);
            union { unsigned short s[8]; uint4 u; } out;
#pragma unroll
            for (int j = 0; j < 8; j++) {
                float v = (c < C_CH) ? wlds[kg * 8 + j][c] : 0.f;
                out.s[j] = f2bf(v);
            }
            *(uint4*)(Bp + ((size_t)((g * 50 + ks * 10 + f) * 64 + l) * 8)) = out.u;
        }
        return;
    }
    if (blk == PACKB_BLKS) {
        for (int i = tid; i < CP * 2; i += 256) {
            int r = i >> 1, c = i & 1;
            Wh2p[i] = (r < C_CH) ? Wh2[r * 2 + c] : 0.f;
        }
        return;
    }
    if (blk < PREP_BLKS) {
        int g = blk - (PACKB_BLKS + 1);      // 0..8
        int c = tid;
        if (c >= CP) return;
        float scale = 1.f, shift = 0.f;
        if (g < 2 * L_LAYERS) {
            int l = g >> 1;
            if ((g & 1) == 0) {
                if (c < C_CH) shift = b1[l * C_CH + c];
            } else if (c < C_CH) {
                float s = gamma[l * C_CH + c] * rsqrtf(rvar[l * C_CH + c] + BN_EPS);
                scale = s;
                shift = (b2[l * C_CH + c] - rmean[l * C_CH + c]) * s + beta[l * C_CH + c];
            }
        } else {
            if (c < C_CH) shift = bh1[c];
        }
        ss[(g * 2 + 0) * CP + c] = scale;
        ss[(g * 2 + 1) * CP + c] = shift;
        return;
    }
    if (blk < PREP_BLKS + FEAT_BLKS) {
        int n = (blk - PREP_BLKS) * 256 + tid;
        if (n < N_NODES) {
            int t = xt[n];                       // 0..31
            int k = xk[n]; k = k < 0 ? 0 : (k > 95 ? 95 : k);
            xtk[n] = (unsigned short)(t | (k << 5));
            float a = xs[2 * n], b = xs[2 * n + 1];
            ht[n]  = packbf(a, b);
            htm[n] = packbf(fmaxf(a, 0.f), fmaxf(b, 0.f));
        }
        return;
    }
    {
        int slot = (blk - PREP_BLKS - FEAT_BLKS) * 256 + tid;
        if (slot < N_NODES / 4)
            ((int4*)indeg)[slot] = make_int4(0, 0, 0, 0);
    }
}

// ---------------------------------------------------------------------------
// CSR-by-dst build: rank from atomic return; fill without atomics
// ---------------------------------------------------------------------------
__global__ void k_indeg(const int* __restrict__ dst, int* __restrict__ indeg,
                        unsigned short* __restrict__ rank16) {
    int e = blockIdx.x * blockDim.x + threadIdx.x;
    if (e >= E_EDGES) return;
    int r = atomicAdd(&indeg[dst[e]], 1);
    __builtin_nontemporal_store((unsigned short)r, &rank16[e]);   // linear -> nt ok
}

__global__ void k_scan1(const int* __restrict__ indeg, int* __restrict__ localscan,
                        int* __restrict__ bsum) {
    __shared__ int lds[256];
    int tid = threadIdx.x;
    int base = blockIdx.x * 1024 + tid * 4;
    int v[4]; int s = 0;
#pragma unroll
    for (int r = 0; r < 4; r++) {
        int i = base + r;
        v[r] = (i < N_NODES) ? indeg[i] : 0;
        s += v[r];
    }
    lds[tid] = s;
    __syncthreads();
    for (int off = 1; off < 256; off <<= 1) {
        int x = (tid >= off) ? lds[tid - off] : 0;
        __syncthreads();
        lds[tid] += x;
        __syncthreads();
    }
    int excl = lds[tid] - s;
    int w = excl;
#pragma unroll
    for (int r = 0; r < 4; r++) {
        int i = base + r;
        if (i < N_NODES) localscan[i] = w;
        w += v[r];
    }
    if (tid == 255) bsum[blockIdx.x] = lds[255];
}

// merged scan2+scan3: each block wave-reduces its exclusive block offset
__global__ void k_scan23(int* __restrict__ rowstart, const int* __restrict__ bsum) {
    __shared__ int offs;
    int tid = threadIdx.x;
    int b = blockIdx.x;
    if (tid < 64) {
        int v = (tid < b) ? bsum[tid] : 0;
#pragma unroll
        for (int m = 1; m < 64; m <<= 1) v += __shfl_xor(v, m, 64);
        if (tid == 0) offs = v;
    }
    __syncthreads();
    int add = offs;
    int base = b * 1024 + tid * 4;
#pragma unroll
    for (int r = 0; r < 4; r++) {
        int i = base + r;
        if (i < N_NODES) rowstart[i] += add;
    }
    if (b == 0 && tid == 0) rowstart[N_NODES] = E_EDGES;
}

// csr[slot] = src | et<<16, slot = rowstart[d] + rank.
// REGULAR store (not nt): scattered 4B stores must linger in L2 so the ~16
// stores per 64B line merge before writeback (nt streamed partial lines ->
// 38MB writeback for 2.4MB payload).
__global__ void k_fill(const int* __restrict__ src, const int* __restrict__ dst,
                       const int* __restrict__ et,
                       const unsigned short* __restrict__ rank16,
                       const int* __restrict__ rowstart, int* __restrict__ csr) {
    int e = blockIdx.x * blockDim.x + threadIdx.x;
    if (e >= E_EDGES) return;
    int d = dst[e];
    csr[rowstart[d] + (int)rank16[e]] = src[e] | (et[e] << 16);
}

// ---------------------------------------------------------------------------
// Aggregation. blocks [0,TAIL_BLKS): tail plane (node/thread).
// blocks [TAIL_BLKS, +MAIN_BLKS): main plane, wave per node.
// L0: index-histogram gather (2B/edge); persists cntf[n].
// L>=1: 4-slot dense gather; cntf hoisted (no per-edge etype work).
// ---------------------------------------------------------------------------
template<bool L0>
__global__ __launch_bounds__(256) void k_spmm(const unsigned* __restrict__ hm,
                                              const unsigned short* __restrict__ xtk,
                                              const unsigned* __restrict__ tmsg,
                                              const unsigned* __restrict__ ht,
                                              const int* __restrict__ rowstart,
                                              const int* __restrict__ csr,
                                              float4* __restrict__ cntf,
                                              unsigned* __restrict__ zm,
                                              unsigned* __restrict__ zt) {
    int b = blockIdx.x;
    if (b < TAIL_BLKS) {
        int n = b * 256 + threadIdx.x;
        if (n >= N_NODES) return;
        unsigned hn = ht[n];
        float a0 = bflo(hn), a1 = bfhi(hn);
        int rs = rowstart[n], re = rowstart[n + 1];
        for (int e = rs; e < re; ++e) {
            unsigned q = tmsg[(unsigned)csr[e] & 0xFFFFu];
            a0 += bflo(q); a1 += bfhi(q);
        }
        __builtin_nontemporal_store(packbf(a0, a1), &zt[n]);
        return;
    }
    int wave = threadIdx.x >> 6;
    int lane = threadIdx.x & 63;
    int n = (b - TAIL_BLKS) * 4 + wave;
    if (n >= N_NODES) return;
    int rs = rowstart[n], re = rowstart[n + 1];

    if (L0) {
        int c0 = 2 * lane, c1 = c0 + 1;
        int ce0 = 0, ce1 = 0, ce2 = 0;
        int xv_s = xtk[n];
        int ts = xv_s & 31, ks = 32 + (xv_s >> 5);
        int ia0 = (ts == c0) + (ks == c0);
        int ia1 = (ts == c1) + (ks == c1);
        for (int e = rs; e < re; e += 16) {
            unsigned p[16]; int xv[16];
#pragma unroll
            for (int r = 0; r < 16; r++) {
                int ee = e + r; ee = (ee < re) ? ee : (re - 1);
                p[r] = (unsigned)csr[ee];
            }
#pragma unroll
            for (int r = 0; r < 16; r++)
                xv[r] = xtk[p[r] & 0xFFFFu];
#pragma unroll
            for (int r = 0; r < 16; r++) {
                if (e + r < re) {
                    int t = xv[r] & 31, k = 32 + (xv[r] >> 5);
                    ia0 += (t == c0) + (k == c0);
                    ia1 += (t == c1) + (k == c1);
                    unsigned et = p[r] >> 16;
                    ce0 += (et == 0); ce1 += (et == 1); ce2 += (et == 2);
                }
            }
        }
        float a0 = (float)ia0, a1 = (float)ia1;
        if (lane == 0) {
            cntf[n] = make_float4((float)ce0, (float)ce1, (float)ce2, 0.f);
            a0 += (float)ce0; a1 += (float)ce1;
        } else if (lane == 1) {
            a0 += (float)ce2;
        }
        __builtin_nontemporal_store(packbf(a0, a1), &zm[(size_t)n * 64 + lane]);
    } else {
        int slot = lane >> 4;        // 0..3: edge subset e%4==slot
        int dw   = lane & 15;        // owns dwords 4dw..4dw+3 (16B)
        float a[8] = {};
        for (int e = rs; e < re; e += 32) {
            unsigned p[8];
            uint4 d[8];
#pragma unroll
            for (int r = 0; r < 8; r++) {
                int ee = e + 4 * r + slot;
                ee = (ee < re) ? ee : (re - 1);
                p[r] = (unsigned)csr[ee] & 0xFFFFu;
            }
#pragma unroll
            for (int r = 0; r < 8; r++)
                d[r] = *(const uint4*)(hm + (size_t)p[r] * 64 + dw * 4);
#pragma unroll
            for (int r = 0; r < 8; r++) {
                if (e + 4 * r + slot < re) {
                    a[0] += bflo(d[r].x); a[1] += bfhi(d[r].x);
                    a[2] += bflo(d[r].y); a[3] += bfhi(d[r].y);
                    a[4] += bflo(d[r].z); a[5] += bfhi(d[r].z);
                    a[6] += bflo(d[r].w); a[7] += bfhi(d[r].w);
                }
            }
        }
#pragma unroll
        for (int m = 16; m <= 32; m <<= 1) {
#pragma unroll
            for (int j = 0; j < 8; j++) a[j] += __shfl_xor(a[j], m, 64);
        }
        if (slot == 0) {
            uint4 hn = *(const uint4*)(hm + (size_t)n * 64 + dw * 4);
            a[0] += bflo(hn.x); a[1] += bfhi(hn.x);
            a[2] += bflo(hn.y); a[3] += bfhi(hn.y);
            a[4] += bflo(hn.z); a[5] += bfhi(hn.z);
            a[6] += bflo(hn.w); a[7] += bfhi(hn.w);
            if (dw == 0) {
                float4 c = cntf[n];
                a[0] += c.x; a[1] += c.y; a[2] += c.z;
            }
            u32x4 o;
            o.x = packbf(a[0], a[1]); o.y = packbf(a[2], a[3]);
            o.z = packbf(a[4], a[5]); o.w = packbf(a[6], a[7]);
            __builtin_nontemporal_store(o, (u32x4*)(zm + (size_t)n * 64 + dw * 4));
        }
    }
}

// ---------------------------------------------------------------------------
// Fused MLP layer, 128-row blocks: h_out = relu(BN(relu(z@W1+b1)@W2+b2))
// Output routed through t_lds -> coalesced nt uint4 stores.
// ---------------------------------------------------------------------------
__global__ __launch_bounds__(256) void k_mlp(const unsigned* __restrict__ zm,
        const unsigned* __restrict__ zt,
        const unsigned short* __restrict__ Bp1, const unsigned short* __restrict__ Bp2,
        const float* __restrict__ sh1, const float* __restrict__ sc2,
        const float* __restrict__ sh2,
        unsigned* __restrict__ hm, unsigned* __restrict__ ht, int M) {
    __shared__ unsigned short t_lds[128 * TS];   // 43008 B
    int tid = threadIdx.x;
    int w = tid >> 6, l = tid & 63;
    int rowg = w >> 1;
    int chh = w & 1;
    int ch = chh * 80;
    int kg = l >> 4;
    int lr = l & 15;
    int mbase = blockIdx.x * 128;

    int rr[4]; bool ok[4];
#pragma unroll
    for (int s = 0; s < 4; s++) { rr[s] = mbase + rowg * 16 + s * 32 + lr; ok[s] = rr[s] < M; }

    f32x4 acc[4][5] = {};
    // ---- stage 1: z @ W1 ----
    for (int ks = 0; ks < 5; ++ks) {
        union { bf16x8 v; uint4 u; } af[4];
#pragma unroll
        for (int s = 0; s < 4; s++) {
            if (ks < 4) af[s].u = ok[s] ? *(const uint4*)(zm + (size_t)rr[s] * 64 + kg * 4 + ks * 16)
                                        : make_uint4(0, 0, 0, 0);
            else        af[s].u = make_uint4((kg == 0 && ok[s]) ? zt[rr[s]] : 0u, 0, 0, 0);
        }
        const unsigned short* bb = Bp1 + ((size_t)((ks * 10 + chh * 5) * 64 + l)) * 8;
#pragma unroll
        for (int f = 0; f < 5; ++f) {
            union { bf16x8 v; uint4 u; } bf;
            bf.u = *(const uint4*)(bb + (size_t)f * 512);
#pragma unroll
            for (int s = 0; s < 4; s++)
                acc[s][f] = __builtin_amdgcn_mfma_f32_16x16x32_bf16(af[s].v, bf.v, acc[s][f], 0, 0, 0);
        }
    }
    // epilogue1: t = relu(acc + b1) -> LDS
#pragma unroll
    for (int f = 0; f < 5; ++f) {
        int c = ch + lr + f * 16;
        float sh = sh1[c];
#pragma unroll
        for (int s = 0; s < 4; s++) {
            int rl = rowg * 16 + s * 32 + kg * 4;
#pragma unroll
            for (int j = 0; j < 4; ++j)
                t_lds[(rl + j) * TS + c] = f2bf(fmaxf(acc[s][f][j] + sh, 0.f));
        }
    }
    __syncthreads();
    // ---- stage 2: t @ W2 ----
#pragma unroll
    for (int s = 0; s < 4; s++)
#pragma unroll
        for (int f = 0; f < 5; ++f) acc[s][f] = (f32x4){0, 0, 0, 0};
    for (int ks = 0; ks < 5; ++ks) {
        union { bf16x8 v; uint4 u; } af[4];
#pragma unroll
        for (int s = 0; s < 4; s++)
            af[s].u = *(const uint4*)(t_lds + (size_t)(rowg * 16 + s * 32 + lr) * TS + ks * 32 + kg * 8);
        const unsigned short* bb = Bp2 + ((size_t)((ks * 10 + chh * 5) * 64 + l)) * 8;
#pragma unroll
        for (int f = 0; f < 5; ++f) {
            union { bf16x8 v; uint4 u; } bf;
            bf.u = *(const uint4*)(bb + (size_t)f * 512);
#pragma unroll
            for (int s = 0; s < 4; s++)
                acc[s][f] = __builtin_amdgcn_mfma_f32_16x16x32_bf16(af[s].v, bf.v, acc[s][f], 0, 0, 0);
        }
    }
    __syncthreads();   // stage-2 reads complete before overwrite
    // epilogue2: BN fold + relu -> LDS (overwrite)
#pragma unroll
    for (int f = 0; f < 5; ++f) {
        int c = ch + lr + f * 16;
        float sc = sc2[c], sh = sh2[c];
#pragma unroll
        for (int s = 0; s < 4; s++) {
            int rl = rowg * 16 + s * 32 + kg * 4;
#pragma unroll
            for (int j = 0; j < 4; ++j)
                t_lds[(rl + j) * TS + c] = f2bf(fmaxf(fmaf(acc[s][f][j], sc, sh), 0.f));
        }
    }
    __syncthreads();
    // coalesced copy-out: 128 rows x 16 uint4 (ch 0..127) + 128 dwords (ch 128/129)
#pragma unroll
    for (int r = 0; r < 9; ++r) {
        int q = tid + 256 * r;
        if (q < 2048) {
            int row = q >> 4;
            int u4 = q & 15;
            int gr = mbase + row;
            if (gr < M) {
                u32x4 v = *(const u32x4*)(t_lds + (size_t)row * TS + u4 * 8);
                __builtin_nontemporal_store(v, (u32x4*)(hm + (size_t)gr * 64 + u4 * 4));
            }
        } else if (q < 2048 + 128) {
            int row = q - 2048;
            int gr = mbase + row;
            if (gr < M) {
                unsigned v = *(const unsigned*)(t_lds + (size_t)row * TS + 128);
                __builtin_nontemporal_store(v, &ht[gr]);
            }
        }
    }
}

// ---------------------------------------------------------------------------
// Fused head: out = relu(h@Wh1+bh1) @ Wh2 + bh2   [N,2] fp32
// ---------------------------------------------------------------------------
__global__ __launch_bounds__(256) void k_head(const unsigned* __restrict__ hm,
        const unsigned* __restrict__ ht, const unsigned short* __restrict__ Bp8,
        const float* __restrict__ sh1, const float* __restrict__ Wh2p,
        const float* __restrict__ bh2, float* __restrict__ out, int M) {
    __shared__ float red[64][2][2];
    int tid = threadIdx.x;
    int w = tid >> 6, l = tid & 63;
    int rowg = w >> 1;
    int chh = w & 1;
    int ch = chh * 80;
    int kg = l >> 4;
    int lr = l & 15;
    int mbase = blockIdx.x * 64;
    int r0 = mbase + rowg * 16 + lr;
    int r1 = r0 + 32;
    bool ok0 = r0 < M, ok1 = r1 < M;

    f32x4 acc0[5] = {}, acc1[5] = {};
    const unsigned* a0p = hm + (size_t)r0 * 64 + kg * 4;
    const unsigned* a1p = hm + (size_t)r1 * 64 + kg * 4;
#pragma unroll
    for (int ks = 0; ks < 5; ++ks) {
        union { bf16x8 v; uint4 u; } af0, af1;
        if (ks < 4) {
            af0.u = ok0 ? *(const uint4*)(a0p + ks * 16) : make_uint4(0, 0, 0, 0);
            af1.u = ok1 ? *(const uint4*)(a1p + ks * 16) : make_uint4(0, 0, 0, 0);
        } else {
            af0.u = make_uint4((kg == 0 && ok0) ? ht[r0] : 0u, 0, 0, 0);
            af1.u = make_uint4((kg == 0 && ok1) ? ht[r1] : 0u, 0, 0, 0);
        }
        const unsigned short* bb = Bp8 + ((size_t)((ks * 10 + chh * 5) * 64 + l)) * 8;
#pragma unroll
        for (int f = 0; f < 5; ++f) {
            union { bf16x8 v; uint4 u; } bf;
            bf.u = *(const uint4*)(bb + (size_t)f * 512);
            acc0[f] = __builtin_amdgcn_mfma_f32_16x16x32_bf16(af0.v, bf.v, acc0[f], 0, 0, 0);
            acc1[f] = __builtin_amdgcn_mfma_f32_16x16x32_bf16(af1.v, bf.v, acc1[f], 0, 0, 0);
        }
    }
    float p0[4][2] = {}, p1[4][2] = {};
#pragma unroll
    for (int f = 0; f < 5; ++f) {
        int c = ch + lr + f * 16;
        float sh = sh1[c];
        float w0 = Wh2p[c * 2], w1 = Wh2p[c * 2 + 1];
#pragma unroll
        for (int j = 0; j < 4; ++j) {
            float u0 = fmaxf(acc0[f][j] + sh, 0.f);
            float u1 = fmaxf(acc1[f][j] + sh, 0.f);
            p0[j][0] = fmaf(u0, w0, p0[j][0]); p0[j][1] = fmaf(u0, w1, p0[j][1]);
            p1[j][0] = fmaf(u1, w0, p1[j][0]); p1[j][1] = fmaf(u1, w1, p1[j][1]);
        }
    }
#pragma unroll
    for (int m = 1; m < 16; m <<= 1) {
#pragma unroll
        for (int j = 0; j < 4; ++j) {
#pragma unroll
            for (int k = 0; k < 2; ++k) {
                p0[j][k] += __shfl_xor(p0[j][k], m, 64);
                p1[j][k] += __shfl_xor(p1[j][k], m, 64);
            }
        }
    }
    if (lr == 0) {
        int rl = rowg * 16 + kg * 4;
#pragma unroll
        for (int j = 0; j < 4; ++j) {
            red[rl + j][chh][0] = p0[j][0];      red[rl + j][chh][1] = p0[j][1];
            red[rl + 32 + j][chh][0] = p1[j][0]; red[rl + 32 + j][chh][1] = p1[j][1];
        }
    }
    __syncthreads();
    if (tid < 128) {
        int r = tid >> 1, k = tid & 1;
        int gr = mbase + r;
        if (gr < M) out[gr * 2 + k] = red[r][0][k] + red[r][1][k] + bh2[k];
    }
}

// ---------------------------------------------------------------------------
extern "C" void kernel_launch(void* const* d_in, const int* in_sizes, int n_in,
                              void* d_out, int out_size, void* d_ws, size_t ws_size,
                              hipStream_t stream) {
    const int* x_type  = (const int*)d_in[0];
    const int* x_tok   = (const int*)d_in[1];
    const float* x_small = (const float*)d_in[2];
    const int* e_src   = (const int*)d_in[3];
    const int* e_dst   = e_src + E_EDGES;
    const int* e_type  = (const int*)d_in[4];
    const float* W1    = (const float*)d_in[6];
    const float* b1    = (const float*)d_in[7];
    const float* W2    = (const float*)d_in[8];
    const float* b2    = (const float*)d_in[9];
    const float* gamma = (const float*)d_in[10];
    const float* beta  = (const float*)d_in[11];
    const float* rmean = (const float*)d_in[12];
    const float* rvar  = (const float*)d_in[13];
    const float* Wh1   = (const float*)d_in[14];
    const float* bh1   = (const float*)d_in[15];
    const float* Wh2   = (const float*)d_in[16];
    const float* bh2   = (const float*)d_in[17];
    float* out = (float*)d_out;

    char* ws = (char*)d_ws;
    size_t o = 0;
    auto take = [&](size_t bytes) -> void* {
        void* p = ws + o;
        o = (o + bytes + 255) & ~(size_t)255;
        return p;
    };
    const size_t HM_BUF = (size_t)N_NODES * 64 * sizeof(unsigned);  // 12.8 MB
    unsigned* hmA = (unsigned*)take(HM_BUF);   // h (layer state)
    unsigned* hmZ = (unsigned*)take(HM_BUF);   // z
    unsigned* htA = (unsigned*)take((size_t)N_NODES * 4);
    unsigned* htZ = (unsigned*)take((size_t)N_NODES * 4);
    unsigned* htM0 = (unsigned*)take((size_t)N_NODES * 4);
    unsigned short* xtk = (unsigned short*)take((size_t)N_NODES * 2);
    unsigned short* Bp = (unsigned short*)take((size_t)9 * 50 * 64 * 8 * sizeof(unsigned short));
    float* Wh2p = (float*)take((size_t)CP * 2 * sizeof(float));
    float* ss   = (float*)take((size_t)9 * 2 * CP * sizeof(float));
    float4* cntf  = (float4*)take((size_t)N_NODES * sizeof(float4));
    int* indeg    = (int*)take((size_t)N_NODES * sizeof(int));
    unsigned short* rank16 = (unsigned short*)take((size_t)E_EDGES * 2);
    int* rowstart = (int*)take((size_t)(N_NODES + 1) * sizeof(int));
    int* bsum     = (int*)take(64 * sizeof(int));
    int* csr      = (int*)take((size_t)E_EDGES * sizeof(int));
    (void)ws_size; (void)in_sizes; (void)n_in; (void)out_size;

    const int NB_SCAN = (N_NODES + 1023) / 1024;  // 49

    // mega prep: weights, epilogue constants, tail feats + xtk, zero indeg
    k_prep<<<PREP_BLKS + FEAT_BLKS + ZERO_BLKS, 256, 0, stream>>>(
        W1, W2, Wh1, Wh2, b1, b2, gamma, beta, rmean, rvar, bh1,
        x_type, x_tok, x_small, Bp, Wh2p, ss, xtk, htA, htM0, indeg);

    // CSR by dst: rank via atomic return, fill without atomics
    k_indeg<<<(E_EDGES + 255) / 256, 256, 0, stream>>>(e_dst, indeg, rank16);
    k_scan1<<<NB_SCAN, 256, 0, stream>>>(indeg, rowstart, bsum);
    k_scan23<<<NB_SCAN, 256, 0, stream>>>(rowstart, bsum);
    k_fill<<<(E_EDGES + 255) / 256, 256, 0, stream>>>(e_src, e_dst, e_type, rank16,
                                                      rowstart, csr);

    // layers
    const int SPMM_GRID = TAIL_BLKS + MAIN_BLKS;
    const int MLP_GRID = (N_NODES + 127) / 128;  // 391
    for (int l = 0; l < L_LAYERS; l++) {
        int g1 = 2 * l, g2 = 2 * l + 1;
        if (l == 0)
            k_spmm<true><<<SPMM_GRID, 256, 0, stream>>>(hmA, xtk, htM0, htA,
                rowstart, csr, cntf, hmZ, htZ);
        else
            k_spmm<false><<<SPMM_GRID, 256, 0, stream>>>(hmA, xtk, htA, htA,
                rowstart, csr, cntf, hmZ, htZ);
        k_mlp<<<MLP_GRID, 256, 0, stream>>>(hmZ, htZ,
            Bp + (size_t)g1 * 25600, Bp + (size_t)g2 * 25600,
            ss + (size_t)(2 * g1 + 1) * CP,
            ss + (size_t)(2 * g2) * CP, ss + (size_t)(2 * g2 + 1) * CP,
            hmA, htA, N_NODES);
    }

    // fused head
    k_head<<<(N_NODES + 63) / 64, 256, 0, stream>>>(hmA, htA, Bp + (size_t)8 * 25600,
        ss + (size_t)(2 * 8 + 1) * CP, Wh2p, bh2, out, N_NODES);
}